// Round 8
// baseline (274.492 us; speedup 1.0000x reference)
//
#include <hip/hip_runtime.h>

#define BB 2
#define SS 2048
#define DDIM 1024
#define HH 16
#define DEPTH 64
#define QKVN (3*DDIM)

typedef unsigned short u16;
typedef unsigned int u32;
typedef __attribute__((ext_vector_type(8))) short bf16x8;
typedef __attribute__((ext_vector_type(4))) float f32x4;

__device__ __forceinline__ u16 f2bf(float f){
  union{float f; u32 u;} z; z.f=f;
  u32 r = z.u + 0x7fffu + ((z.u>>16)&1u);
  return (u16)(r>>16);
}
#define NEG_BIG (-1e30f)

// async global->LDS, 16B per lane (guide m97); LDS dest must be wave-linear (ours is tid*16B)
#define GL2LDS(gp, lp) __builtin_amdgcn_global_load_lds( \
    (const __attribute__((address_space(1))) void*)(gp), \
    (__attribute__((address_space(3))) void*)(lp), 16, 0, 0)

// ---------------- transpose+convert f32 [R,C] -> bf16 [C,R] ----------------
__global__ void convT_k(const float* __restrict__ in, u16* __restrict__ out, int R, int C){
  __shared__ float tile[32][33];
  int c0 = blockIdx.x<<5, r0 = blockIdx.y<<5;
  int tx = threadIdx.x, ty = threadIdx.y;
  for (int i=ty;i<32;i+=8) tile[i][tx] = in[(size_t)(r0+i)*C + c0+tx];
  __syncthreads();
  for (int i=ty;i<32;i+=8) out[(size_t)(c0+i)*R + r0+tx] = f2bf(tile[tx][i]);
}

// ---------------- convert f32 -> bf16 flat (both batches) ----------------
__global__ void convX_k(const float* __restrict__ in, u16* __restrict__ out){
  size_t i = ((size_t)blockIdx.x*256 + threadIdx.x) * 8;
  float4 a = *(const float4*)(in + i);
  float4 b = *(const float4*)(in + i + 4);
  ushort4 lo = { f2bf(a.x), f2bf(a.y), f2bf(a.z), f2bf(a.w) };
  ushort4 hi = { f2bf(b.x), f2bf(b.y), f2bf(b.z), f2bf(b.w) };
  *(ushort4*)(out + i)     = lo;
  *(ushort4*)(out + i + 4) = hi;
}

// ---------------- QKV GEMM (m97-style: global_load_lds staging) ----------------
// [4096,1024]@[1024,3072]^T. Epilogue splits into Qb (x0.125), Kb, Vt (V transposed).
__global__ __launch_bounds__(256,2) void gemm_qkv_k(
    const u16* __restrict__ A, const u16* __restrict__ Bt,
    const float* __restrict__ bias,
    u16* __restrict__ Qb, u16* __restrict__ Kb, u16* __restrict__ Vt)
{
  const int K = DDIM;
  __shared__ __align__(16) u16 As[128*32];
  __shared__ __align__(16) u16 Bs[128*32];
  const int tid = threadIdx.x;
  const int m0 = blockIdx.x<<7, n0 = blockIdx.y<<7;
  const int w = tid>>6, lane = tid&63, q = lane>>4, ln = lane&15;
  const int wr = (w>>1)<<6, wc = (w&1)<<6;

  f32x4 acc[4][4];
  #pragma unroll
  for (int i=0;i<4;i++)
    #pragma unroll
    for (int j=0;j<4;j++) acc[i][j] = (f32x4){0.f,0.f,0.f,0.f};

  const int row0 = tid>>2,         off0 = (tid&3)<<3;
  const int row1 = (tid+256)>>2,   off1 = (tid&3)<<3;   // (tid+256)&3 == tid&3

  for (int k0=0;k0<K;k0+=32){
    GL2LDS(&A [(size_t)(m0+row0)*K + k0 + off0], &As[(row0<<5)+off0]);
    GL2LDS(&Bt[(size_t)(n0+row0)*K + k0 + off0], &Bs[(row0<<5)+off0]);
    GL2LDS(&A [(size_t)(m0+row1)*K + k0 + off1], &As[(row1<<5)+off1]);
    GL2LDS(&Bt[(size_t)(n0+row1)*K + k0 + off1], &Bs[(row1<<5)+off1]);
    __syncthreads();
    bf16x8 af[4], bfr[4];
    #pragma unroll
    for (int i=0;i<4;i++) af[i]  = *(const bf16x8*)&As[((wr + (i<<4) + ln)<<5) + (q<<3)];
    #pragma unroll
    for (int j=0;j<4;j++) bfr[j] = *(const bf16x8*)&Bs[((wc + (j<<4) + ln)<<5) + (q<<3)];
    #pragma unroll
    for (int i=0;i<4;i++)
      #pragma unroll
      for (int j=0;j<4;j++)
        acc[i][j] = __builtin_amdgcn_mfma_f32_16x16x32_bf16(af[i], bfr[j], acc[i][j], 0, 0, 0);
    __syncthreads();
  }

  #pragma unroll
  for (int i=0;i<4;i++){
    const int mmb = m0 + wr + (i<<4) + (q<<2);         // global row (4096 range)
    const int bsel = mmb >> 11;                        // batch (uniform per block)
    const int sb   = mmb & 2047;                       // s within batch
    #pragma unroll
    for (int j=0;j<4;j++){
      const int n = n0 + wc + (j<<4) + ln;
      const int h = n / 192;
      const int rr = n - h*192;
      const int bh = (bsel<<4) + h;
      const float bv = bias[n];
      if (rr < 64){                                    // Q, scaled by 1/8
        u16* dst = Qb + (size_t)bh*SS*DEPTH + rr;
        #pragma unroll
        for (int r=0;r<4;r++) dst[(size_t)(sb+r)*DEPTH] = f2bf((acc[i][j][r] + bv)*0.125f);
      } else if (rr < 128){                            // K
        u16* dst = Kb + (size_t)bh*SS*DEPTH + (rr-64);
        #pragma unroll
        for (int r=0;r<4;r++) dst[(size_t)(sb+r)*DEPTH] = f2bf(acc[i][j][r] + bv);
      } else {                                         // V transposed: Vt[bh][d][s]
        ushort4 pv = { f2bf(acc[i][j][0] + bv), f2bf(acc[i][j][1] + bv),
                       f2bf(acc[i][j][2] + bv), f2bf(acc[i][j][3] + bv) };
        *(ushort4*)(Vt + ((size_t)bh*DEPTH + (rr-128))*SS + sb) = pv;
      }
    }
  }
}

// ---------------- MFMA flash attention: QBLK=128 (2 row-tiles/wave) ----------------
// vs round 7: each block covers 128 q-rows (wave owns rt=0,1 16-row fragments).
// Tile-iter count halves (16896 -> 8704); staging, barriers, and vf reads are
// amortized over 2x the output.  Causality: rt0 skips last tile (fully masked);
// rt0 masks diagonally at t==T-2, rt1 at t==T-1 (wave-uniform branches).
// Keeps: T14 async-stage, 2 barriers/iter, MFMA ones-column row-sum.
__global__ __launch_bounds__(256,4) void attn_k(
    u16* __restrict__ Qb, const u16* __restrict__ Kb, const u16* __restrict__ Vt)
{
  __shared__ __align__(16) u16 Ks[64*72];      // K tile [j][d], stride 72
  __shared__ __align__(16) u16 VsT[64*72];     // V^T tile [d][j], stride 72
  __shared__ __align__(16) u16 ps[4][32*72];   // per-wave P [rt*16+m][j], stride 72

  const int tid = threadIdx.x, w = tid>>6, lane = tid&63, q = lane>>4, ln = lane&15;
  const int bh = blockIdx.x;                   // b*16 + h  (XCD = bh%8)
  const int y  = blockIdx.y;                   // 16 slots; heavy half dispatched first
  const int qt = (y<8) ? 15-y : y-8;
  const int r0 = qt<<7;                        // 128-row q-tile base
  const size_t kbase = (size_t)bh*SS*DEPTH;    // Kb/Qb per-(b,h) base
  const size_t vbase = (size_t)bh*DEPTH*SS;    // Vt per-(b,h) base
  const u16* __restrict__ Kp = Kb + kbase;
  const u16* __restrict__ Vp = Vt + vbase;

  // staging geometry: chunk c = p*256+tid covers (j = c>>3, d = (c&7)*8), 512 chunks
  const int j0 = tid>>3,      d0 = (tid&7)<<3;   // p=0
  const int j1 = j0 + 32,     d1 = d0;           // p=1

  bf16x8 qf[2][2];
  #pragma unroll
  for (int rt=0;rt<2;rt++)
    #pragma unroll
    for (int ks=0;ks<2;ks++)
      qf[rt][ks] = *(const bf16x8*)(Qb + kbase +
          (size_t)(r0 + (rt<<6) + (w<<4) + ln)*DEPTH + (ks<<5) + (q<<3));

  const bf16x8 vone = { (short)0x3F80, (short)0x3F80, (short)0x3F80, (short)0x3F80,
                        (short)0x3F80, (short)0x3F80, (short)0x3F80, (short)0x3F80 };

  f32x4 o[2][4];
  #pragma unroll
  for (int rt=0;rt<2;rt++)
    #pragma unroll
    for (int nt=0;nt<4;nt++) o[rt][nt] = (f32x4){0.f,0.f,0.f,0.f};
  f32x4 lacc[2];
  lacc[0] = (f32x4){0.f,0.f,0.f,0.f}; lacc[1] = (f32x4){0.f,0.f,0.f,0.f};
  float m_r[2][4];
  #pragma unroll
  for (int rt=0;rt<2;rt++)
    #pragma unroll
    for (int r=0;r<4;r++) m_r[rt][r] = NEG_BIG;

  uint4 kr0, kr1, vr0, vr1;
  #define LOADT(t) do { \
    kr0 = *(const uint4*)(Kp + (size_t)(((t)<<6)+j0)*DEPTH + d0); \
    kr1 = *(const uint4*)(Kp + (size_t)(((t)<<6)+j1)*DEPTH + d1); \
    vr0 = *(const uint4*)(Vp + (size_t)j0*SS + ((t)<<6) + d0); \
    vr1 = *(const uint4*)(Vp + (size_t)j1*SS + ((t)<<6) + d1); } while(0)

  const int T = (qt<<1) + 2;
  LOADT(0);                                    // prefetch tile 0
  for (int t=0;t<T;t++){
    if (t) __syncthreads();                    // all waves done reading tile t-1
    *(uint4*)&Ks [j0*72 + d0] = kr0;           // write tile t (regs already resident)
    *(uint4*)&Ks [j1*72 + d1] = kr1;
    *(uint4*)&VsT[j0*72 + d0] = vr0;
    *(uint4*)&VsT[j1*72 + d1] = vr1;
    if (t+1 < T) LOADT(t+1);                   // issue next tile's loads; land under compute
    __syncthreads();                           // tile t visible

    #pragma unroll
    for (int rt=0;rt<2;rt++){
      if (rt==0 && t==T-1) continue;           // rt0 fully masked on last tile (uniform)

      // QK^T for this row-tile
      f32x4 sc[4];
      #pragma unroll
      for (int jt=0;jt<4;jt++) sc[jt] = (f32x4){0.f,0.f,0.f,0.f};
      #pragma unroll
      for (int ks=0;ks<2;ks++){
        #pragma unroll
        for (int jt=0;jt<4;jt++){
          bf16x8 kf = *(const bf16x8*)&Ks[((jt<<4)+ln)*72 + (ks<<5) + (q<<3)];
          sc[jt] = __builtin_amdgcn_mfma_f32_16x16x32_bf16(qf[rt][ks], kf, sc[jt], 0, 0, 0);
        }
      }

      // causal mask on this row-tile's diagonal tile (rt0: t==T-2, rt1: t==T-1)
      if (t == T-2+rt){
        const int rowb = r0 + (rt<<6) + (w<<4) + (q<<2);
        #pragma unroll
        for (int jt=0;jt<4;jt++){
          const int col = (t<<6) + (jt<<4) + ln;
          #pragma unroll
          for (int r=0;r<4;r++)
            if (col > rowb + r) sc[jt][r] = NEG_BIG;
        }
      }

      // online softmax: MAX butterfly only (sum via ones-column MFMA)
      float alpha_r[4];
      #pragma unroll
      for (int r=0;r<4;r++){
        float mt = fmaxf(fmaxf(sc[0][r], sc[1][r]), fmaxf(sc[2][r], sc[3][r]));
        #pragma unroll
        for (int off=1; off<16; off<<=1) mt = fmaxf(mt, __shfl_xor(mt, off));
        const float mnew = fmaxf(m_r[rt][r], mt);
        alpha_r[r] = __expf(m_r[rt][r] - mnew);
        float p0 = __expf(sc[0][r]-mnew), p1 = __expf(sc[1][r]-mnew);
        float p2 = __expf(sc[2][r]-mnew), p3 = __expf(sc[3][r]-mnew);
        const int mrow = (rt<<4) + (q<<2) + r;
        ps[w][mrow*72 +      ln] = f2bf(p0);
        ps[w][mrow*72 + 16 + ln] = f2bf(p1);
        ps[w][mrow*72 + 32 + ln] = f2bf(p2);
        ps[w][mrow*72 + 48 + ln] = f2bf(p3);
        m_r[rt][r] = mnew;
      }
      #pragma unroll
      for (int r=0;r<4;r++){
        lacc[rt][r] *= alpha_r[r];
        #pragma unroll
        for (int nt=0;nt<4;nt++) o[rt][nt][r] *= alpha_r[r];
      }
    }

    // PV + row-sum; vf reads shared across both row-tiles (ps per-wave: lgkmcnt orders)
    const bool rt0a = (t < T-1);
    #pragma unroll
    for (int ks=0;ks<2;ks++){
      bf16x8 pa1 = *(const bf16x8*)&ps[w][(16+ln)*72 + (ks<<5) + (q<<3)];
      bf16x8 pa0;
      lacc[1] = __builtin_amdgcn_mfma_f32_16x16x32_bf16(pa1, vone, lacc[1], 0, 0, 0);
      if (rt0a){
        pa0 = *(const bf16x8*)&ps[w][ln*72 + (ks<<5) + (q<<3)];
        lacc[0] = __builtin_amdgcn_mfma_f32_16x16x32_bf16(pa0, vone, lacc[0], 0, 0, 0);
      }
      #pragma unroll
      for (int nt=0;nt<4;nt++){
        bf16x8 vf = *(const bf16x8*)&VsT[((nt<<4)+ln)*72 + (ks<<5) + (q<<3)];
        o[1][nt] = __builtin_amdgcn_mfma_f32_16x16x32_bf16(pa1, vf, o[1][nt], 0, 0, 0);
        if (rt0a)
          o[0][nt] = __builtin_amdgcn_mfma_f32_16x16x32_bf16(pa0, vf, o[0][nt], 0, 0, 0);
      }
    }
  }
  #undef LOADT

  // epilogue: o/l -> bf16, overwrite this block's own Qb rows
  #pragma unroll
  for (int rt=0;rt<2;rt++){
    #pragma unroll
    for (int r=0;r<4;r++){
      const float rl = 1.f / fmaxf(lacc[rt][r], 1e-30f);
      const int s = r0 + (rt<<6) + (w<<4) + (q<<2) + r;
      #pragma unroll
      for (int nt=0;nt<4;nt++)
        Qb[kbase + (size_t)s*DEPTH + (nt<<4) + ln] = f2bf(o[rt][nt][r] * rl);
    }
  }
}

// ---------------- out projection: 64x128 tile, 512 blocks = 2/CU ----------------
// A(m,k) = Qb[(m>>11)*16 + k/64][m&2047][k%64]
__global__ __launch_bounds__(256,2) void gemm_out_k(
    const u16* __restrict__ Aq, const u16* __restrict__ Bt,
    const float* __restrict__ bias, float* __restrict__ out)
{
  const int K = DDIM;
  __shared__ __align__(16) u16 As[64*32];
  __shared__ __align__(16) u16 Bs[128*32];
  const int tid = threadIdx.x;
  const int m0 = blockIdx.x<<6, n0 = blockIdx.y<<7;
  const int bsel = m0>>11, ms = m0&2047;       // batch select (uniform per block)
  const int w = tid>>6, lane = tid&63, q = lane>>4, ln = lane&15;
  const int wr = (w>>1)<<5, wc = (w&1)<<6;     // wave: 32 rows x 64 cols

  f32x4 acc[2][4];
  #pragma unroll
  for (int i=0;i<2;i++)
    #pragma unroll
    for (int j=0;j<4;j++) acc[i][j] = (f32x4){0.f,0.f,0.f,0.f};

  const int rowA  = tid>>2,       offA = (tid&3)<<3;   // 64 rows x 4 chunks = 256
  const int rowB0 = tid>>2,       offB = (tid&3)<<3;   // 128 rows x 4 chunks = 512
  const int rowB1 = (tid+256)>>2;

  for (int k0=0;k0<K;k0+=32){
    const size_t abase = (size_t)((bsel<<4) + (k0>>6))*SS*DEPTH + (k0&63);
    GL2LDS(&Aq[abase + (size_t)(ms+rowA)*DEPTH + offA], &As[(rowA<<5)+offA]);
    GL2LDS(&Bt[(size_t)(n0+rowB0)*K + k0 + offB],       &Bs[(rowB0<<5)+offB]);
    GL2LDS(&Bt[(size_t)(n0+rowB1)*K + k0 + offB],       &Bs[(rowB1<<5)+offB]);
    __syncthreads();
    bf16x8 af[2], bfr[4];
    #pragma unroll
    for (int i=0;i<2;i++) af[i]  = *(const bf16x8*)&As[((wr + (i<<4) + ln)<<5) + (q<<3)];
    #pragma unroll
    for (int j=0;j<4;j++) bfr[j] = *(const bf16x8*)&Bs[((wc + (j<<4) + ln)<<5) + (q<<3)];
    #pragma unroll
    for (int i=0;i<2;i++)
      #pragma unroll
      for (int j=0;j<4;j++)
        acc[i][j] = __builtin_amdgcn_mfma_f32_16x16x32_bf16(af[i], bfr[j], acc[i][j], 0, 0, 0);
    __syncthreads();
  }

  #pragma unroll
  for (int i=0;i<2;i++){
    #pragma unroll
    for (int j=0;j<4;j++){
      const int n = n0 + wc + (j<<4) + ln;
      const float bv = bias[n];
      #pragma unroll
      for (int r=0;r<4;r++){
        const int mm = m0 + wr + (i<<4) + (q<<2) + r;
        out[(size_t)mm*DDIM + n] = acc[i][j][r] + bv;
      }
    }
  }
}

extern "C" void kernel_launch(void* const* d_in, const int* in_sizes, int n_in,
                              void* d_out, int out_size, void* d_ws, size_t ws_size,
                              hipStream_t stream)
{
  int ix = 0, iw = 2, ibq = 3, iwo = 4, ibo = 5;
  if (n_in == 5){ iw = 1; ibq = 2; iwo = 3; ibo = 4; }
  const float* x  = (const float*)d_in[ix];
  const float* Wq = (const float*)d_in[iw];
  const float* bq = (const float*)d_in[ibq];
  const float* Wo = (const float*)d_in[iwo];
  const float* bo = (const float*)d_in[ibo];
  float* out = (float*)d_out;

  // workspace (u16 units), total 41,943,040 B — round-1-proven footprint
  u16* ws  = (u16*)d_ws;
  u16* Wqt = ws;                                   // [3072,1024] bf16
  u16* Wot = Wqt + (size_t)QKVN*DDIM;              // [1024,1024] bf16 (bt form)
  u16* Qb  = Wot + (size_t)DDIM*DDIM;              // [B*H][S][64]; attn out aliases here
  u16* Kb  = Qb  + (size_t)BB*HH*SS*DEPTH;         // [B*H][S][64]
  u16* Vt  = Kb  + (size_t)BB*HH*SS*DEPTH;         // [B*H][64][S] (V transposed)
  u16* xb  = Vt  + (size_t)BB*HH*SS*DEPTH;         // [2,2048,1024] bf16

  convT_k<<<dim3(QKVN/32, DDIM/32), dim3(32,8), 0, stream>>>(Wq, Wqt, DDIM, QKVN);
  convT_k<<<dim3(DDIM/32, DDIM/32), dim3(32,8), 0, stream>>>(Wo, Wot, DDIM, DDIM);
  convX_k<<<dim3(BB*SS*DDIM/2048), 256, 0, stream>>>(x, xb);

  gemm_qkv_k<<<dim3(BB*SS/128, QKVN/128), 256, 0, stream>>>(xb, Wqt, bq, Qb, Kb, Vt);
  attn_k    <<<dim3(BB*HH, 16),           256, 0, stream>>>(Qb, Kb, Vt);
  gemm_out_k<<<dim3(BB*SS/64,  DDIM/128), 256, 0, stream>>>(Qb, Wot, bo, out);
}

// Round 15
// 212.393 us; speedup vs baseline: 1.2924x; 1.2924x over previous
//
#include <hip/hip_runtime.h>

#define BB 2
#define SS 2048
#define DDIM 1024
#define HH 16
#define DEPTH 64
#define QKVN (3*DDIM)

typedef unsigned short u16;
typedef unsigned int u32;
typedef __attribute__((ext_vector_type(8))) short bf16x8;
typedef __attribute__((ext_vector_type(4))) float f32x4;

__device__ __forceinline__ u16 f2bf(float f){
  union{float f; u32 u;} z; z.f=f;
  u32 r = z.u + 0x7fffu + ((z.u>>16)&1u);
  return (u16)(r>>16);
}
#define NEG_BIG (-1e30f)

// async global->LDS, 16B per lane (guide m97); LDS dest must be wave-linear (ours is tid*16B)
#define GL2LDS(gp, lp) __builtin_amdgcn_global_load_lds( \
    (const __attribute__((address_space(1))) void*)(gp), \
    (__attribute__((address_space(3))) void*)(lp), 16, 0, 0)

// ---------------- transpose+convert f32 [R,C] -> bf16 [C,R] ----------------
__global__ void convT_k(const float* __restrict__ in, u16* __restrict__ out, int R, int C){
  __shared__ float tile[32][33];
  int c0 = blockIdx.x<<5, r0 = blockIdx.y<<5;
  int tx = threadIdx.x, ty = threadIdx.y;
  for (int i=ty;i<32;i+=8) tile[i][tx] = in[(size_t)(r0+i)*C + c0+tx];
  __syncthreads();
  for (int i=ty;i<32;i+=8) out[(size_t)(c0+i)*R + r0+tx] = f2bf(tile[tx][i]);
}

// ---------------- convert f32 -> bf16 flat (both batches) ----------------
__global__ void convX_k(const float* __restrict__ in, u16* __restrict__ out){
  size_t i = ((size_t)blockIdx.x*256 + threadIdx.x) * 8;
  float4 a = *(const float4*)(in + i);
  float4 b = *(const float4*)(in + i + 4);
  ushort4 lo = { f2bf(a.x), f2bf(a.y), f2bf(a.z), f2bf(a.w) };
  ushort4 hi = { f2bf(b.x), f2bf(b.y), f2bf(b.z), f2bf(b.w) };
  *(ushort4*)(out + i)     = lo;
  *(ushort4*)(out + i + 4) = hi;
}

// ---------------- QKV GEMM (m97-style: global_load_lds staging) ----------------
// [4096,1024]@[1024,3072]^T. Epilogue splits into Qb (x0.125), Kb, Vt (V transposed).
__global__ __launch_bounds__(256,2) void gemm_qkv_k(
    const u16* __restrict__ A, const u16* __restrict__ Bt,
    const float* __restrict__ bias,
    u16* __restrict__ Qb, u16* __restrict__ Kb, u16* __restrict__ Vt)
{
  const int K = DDIM;
  __shared__ __align__(16) u16 As[128*32];
  __shared__ __align__(16) u16 Bs[128*32];
  const int tid = threadIdx.x;
  const int m0 = blockIdx.x<<7, n0 = blockIdx.y<<7;
  const int w = tid>>6, lane = tid&63, q = lane>>4, ln = lane&15;
  const int wr = (w>>1)<<6, wc = (w&1)<<6;

  f32x4 acc[4][4];
  #pragma unroll
  for (int i=0;i<4;i++)
    #pragma unroll
    for (int j=0;j<4;j++) acc[i][j] = (f32x4){0.f,0.f,0.f,0.f};

  const int row0 = tid>>2,         off0 = (tid&3)<<3;
  const int row1 = (tid+256)>>2,   off1 = (tid&3)<<3;   // (tid+256)&3 == tid&3

  for (int k0=0;k0<K;k0+=32){
    GL2LDS(&A [(size_t)(m0+row0)*K + k0 + off0], &As[(row0<<5)+off0]);
    GL2LDS(&Bt[(size_t)(n0+row0)*K + k0 + off0], &Bs[(row0<<5)+off0]);
    GL2LDS(&A [(size_t)(m0+row1)*K + k0 + off1], &As[(row1<<5)+off1]);
    GL2LDS(&Bt[(size_t)(n0+row1)*K + k0 + off1], &Bs[(row1<<5)+off1]);
    __syncthreads();
    bf16x8 af[4], bfr[4];
    #pragma unroll
    for (int i=0;i<4;i++) af[i]  = *(const bf16x8*)&As[((wr + (i<<4) + ln)<<5) + (q<<3)];
    #pragma unroll
    for (int j=0;j<4;j++) bfr[j] = *(const bf16x8*)&Bs[((wc + (j<<4) + ln)<<5) + (q<<3)];
    #pragma unroll
    for (int i=0;i<4;i++)
      #pragma unroll
      for (int j=0;j<4;j++)
        acc[i][j] = __builtin_amdgcn_mfma_f32_16x16x32_bf16(af[i], bfr[j], acc[i][j], 0, 0, 0);
    __syncthreads();
  }

  #pragma unroll
  for (int i=0;i<4;i++){
    const int mmb = m0 + wr + (i<<4) + (q<<2);         // global row (4096 range)
    const int bsel = mmb >> 11;                        // batch (uniform per block)
    const int sb   = mmb & 2047;                       // s within batch
    #pragma unroll
    for (int j=0;j<4;j++){
      const int n = n0 + wc + (j<<4) + ln;
      const int h = n / 192;
      const int rr = n - h*192;
      const int bh = (bsel<<4) + h;
      const float bv = bias[n];
      if (rr < 64){                                    // Q, scaled by 1/8
        u16* dst = Qb + (size_t)bh*SS*DEPTH + rr;
        #pragma unroll
        for (int r=0;r<4;r++) dst[(size_t)(sb+r)*DEPTH] = f2bf((acc[i][j][r] + bv)*0.125f);
      } else if (rr < 128){                            // K
        u16* dst = Kb + (size_t)bh*SS*DEPTH + (rr-64);
        #pragma unroll
        for (int r=0;r<4;r++) dst[(size_t)(sb+r)*DEPTH] = f2bf(acc[i][j][r] + bv);
      } else {                                         // V transposed: Vt[bh][d][s]
        ushort4 pv = { f2bf(acc[i][j][0] + bv), f2bf(acc[i][j][1] + bv),
                       f2bf(acc[i][j][2] + bv), f2bf(acc[i][j][3] + bv) };
        *(ushort4*)(Vt + ((size_t)bh*DEPTH + (rr-128))*SS + sb) = pv;
      }
    }
  }
}

// ---------------- MFMA flash attention (round-7 structure, QBLK=64) ----------------
// T14 async-stage + 2 barriers + MFMA ones-column row-sum (all proven).
// Round-10 change (ONLY): __launch_bounds__(256,5) -- VGPR=60 and LDS=27,648B allow
// 5 blocks/CU (floor(160KB/27.6KB)=5); the old (256,4) declaration was the cap.
// +25% co-resident independent blocks in a latency-bound regime (occupancy 30%).
__global__ __launch_bounds__(256,5) void attn_k(
    u16* __restrict__ Qb, const u16* __restrict__ Kb, const u16* __restrict__ Vt)
{
  __shared__ __align__(16) u16 Ks[64*72];      // K tile [j][d], stride 72
  __shared__ __align__(16) u16 VsT[64*72];     // V^T tile [d][j], stride 72
  __shared__ __align__(16) u16 ps[4][16*72];   // per-wave P [m][j], stride 72

  const int tid = threadIdx.x, w = tid>>6, lane = tid&63, q = lane>>4, ln = lane&15;
  const int bh = blockIdx.x;                   // b*16 + h  (XCD = bh%8)
  const int y  = blockIdx.y, sgrp = y>>3, rr_ = y&7;
  const int qt = (sgrp==0) ? 31-rr_ : (sgrp==1) ? 16+rr_ : (sgrp==2) ? 15-rr_ : rr_;
  const int r0 = qt<<6;
  const size_t kbase = (size_t)bh*SS*DEPTH;    // Kb/Qb per-(b,h) base
  const size_t vbase = (size_t)bh*DEPTH*SS;    // Vt per-(b,h) base
  const u16* __restrict__ Kp = Kb + kbase;
  const u16* __restrict__ Vp = Vt + vbase;

  // staging geometry: chunk c = p*256+tid covers (j = c>>3, d = (c&7)*8), 512 chunks
  const int j0 = tid>>3,      d0 = (tid&7)<<3;   // p=0
  const int j1 = j0 + 32,     d1 = d0;           // p=1

  bf16x8 qf[2];
  #pragma unroll
  for (int ks=0;ks<2;ks++)
    qf[ks] = *(const bf16x8*)(Qb + kbase + (size_t)(r0 + (w<<4) + ln)*DEPTH + (ks<<5) + (q<<3));

  const bf16x8 vone = { (short)0x3F80, (short)0x3F80, (short)0x3F80, (short)0x3F80,
                        (short)0x3F80, (short)0x3F80, (short)0x3F80, (short)0x3F80 };

  f32x4 o[4];
  #pragma unroll
  for (int nt=0;nt<4;nt++) o[nt] = (f32x4){0.f,0.f,0.f,0.f};
  f32x4 lacc = (f32x4){0.f,0.f,0.f,0.f};
  float m_r[4];
  #pragma unroll
  for (int r=0;r<4;r++) m_r[r] = NEG_BIG;

  uint4 kr0, kr1, vr0, vr1;
  #define LOADT(t) do { \
    kr0 = *(const uint4*)(Kp + (size_t)(((t)<<6)+j0)*DEPTH + d0); \
    kr1 = *(const uint4*)(Kp + (size_t)(((t)<<6)+j1)*DEPTH + d1); \
    vr0 = *(const uint4*)(Vp + (size_t)j0*SS + ((t)<<6) + d0); \
    vr1 = *(const uint4*)(Vp + (size_t)j1*SS + ((t)<<6) + d1); } while(0)

  const int T = qt + 1;
  LOADT(0);                                    // prefetch tile 0
  for (int t=0;t<T;t++){
    if (t) __syncthreads();                    // all waves done reading tile t-1
    *(uint4*)&Ks [j0*72 + d0] = kr0;           // write tile t (regs already resident)
    *(uint4*)&Ks [j1*72 + d1] = kr1;
    *(uint4*)&VsT[j0*72 + d0] = vr0;
    *(uint4*)&VsT[j1*72 + d1] = vr1;
    if (t+1 < T) LOADT(t+1);                   // issue next tile's loads; land under compute
    __syncthreads();                           // tile t visible

    // QK^T
    f32x4 sc[4];
    #pragma unroll
    for (int jt=0;jt<4;jt++) sc[jt] = (f32x4){0.f,0.f,0.f,0.f};
    #pragma unroll
    for (int ks=0;ks<2;ks++){
      #pragma unroll
      for (int jt=0;jt<4;jt++){
        bf16x8 kf = *(const bf16x8*)&Ks[((jt<<4)+ln)*72 + (ks<<5) + (q<<3)];
        sc[jt] = __builtin_amdgcn_mfma_f32_16x16x32_bf16(qf[ks], kf, sc[jt], 0, 0, 0);
      }
    }

    // causal mask on diagonal tile
    if (t == T-1){
      const int rowb = r0 + (w<<4) + (q<<2);
      #pragma unroll
      for (int jt=0;jt<4;jt++){
        const int col = (t<<6) + (jt<<4) + ln;
        #pragma unroll
        for (int r=0;r<4;r++)
          if (col > rowb + r) sc[jt][r] = NEG_BIG;
      }
    }

    // online softmax per row: MAX butterfly only (sum via ones-column MFMA)
    float alpha_r[4];
    #pragma unroll
    for (int r=0;r<4;r++){
      float mt = fmaxf(fmaxf(sc[0][r], sc[1][r]), fmaxf(sc[2][r], sc[3][r]));
      #pragma unroll
      for (int off=1; off<16; off<<=1) mt = fmaxf(mt, __shfl_xor(mt, off));
      const float mnew = fmaxf(m_r[r], mt);
      alpha_r[r] = __expf(m_r[r] - mnew);
      float p0 = __expf(sc[0][r]-mnew), p1 = __expf(sc[1][r]-mnew);
      float p2 = __expf(sc[2][r]-mnew), p3 = __expf(sc[3][r]-mnew);
      const int mrow = (q<<2) + r;
      ps[w][mrow*72 +      ln] = f2bf(p0);
      ps[w][mrow*72 + 16 + ln] = f2bf(p1);
      ps[w][mrow*72 + 32 + ln] = f2bf(p2);
      ps[w][mrow*72 + 48 + ln] = f2bf(p3);
      m_r[r] = mnew;
    }
    #pragma unroll
    for (int r=0;r<4;r++){
      lacc[r] *= alpha_r[r];
      #pragma unroll
      for (int nt=0;nt<4;nt++) o[nt][r] *= alpha_r[r];
    }

    // PV + row-sum (ps is per-wave: no barrier needed, lgkmcnt orders the RAW)
    #pragma unroll
    for (int ks=0;ks<2;ks++){
      bf16x8 pa = *(const bf16x8*)&ps[w][ln*72 + (ks<<5) + (q<<3)];
      lacc = __builtin_amdgcn_mfma_f32_16x16x32_bf16(pa, vone, lacc, 0, 0, 0);
      #pragma unroll
      for (int nt=0;nt<4;nt++){
        bf16x8 vf = *(const bf16x8*)&VsT[((nt<<4)+ln)*72 + (ks<<5) + (q<<3)];
        o[nt] = __builtin_amdgcn_mfma_f32_16x16x32_bf16(pa, vf, o[nt], 0, 0, 0);
      }
    }
  }
  #undef LOADT

  // epilogue: o/l -> bf16, overwrite this block's own Qb rows
  #pragma unroll
  for (int r=0;r<4;r++){
    const float rl = 1.f / fmaxf(lacc[r], 1e-30f);
    const int s = r0 + (w<<4) + (q<<2) + r;
    #pragma unroll
    for (int nt=0;nt<4;nt++)
      Qb[kbase + (size_t)s*DEPTH + (nt<<4) + ln] = f2bf(o[nt][r] * rl);
  }
}

// ---------------- out projection: 64x128 tile, 512 blocks = 2/CU ----------------
// A(m,k) = Qb[(m>>11)*16 + k/64][m&2047][k%64]
__global__ __launch_bounds__(256,2) void gemm_out_k(
    const u16* __restrict__ Aq, const u16* __restrict__ Bt,
    const float* __restrict__ bias, float* __restrict__ out)
{
  const int K = DDIM;
  __shared__ __align__(16) u16 As[64*32];
  __shared__ __align__(16) u16 Bs[128*32];
  const int tid = threadIdx.x;
  const int m0 = blockIdx.x<<6, n0 = blockIdx.y<<7;
  const int bsel = m0>>11, ms = m0&2047;       // batch select (uniform per block)
  const int w = tid>>6, lane = tid&63, q = lane>>4, ln = lane&15;
  const int wr = (w>>1)<<5, wc = (w&1)<<6;     // wave: 32 rows x 64 cols

  f32x4 acc[2][4];
  #pragma unroll
  for (int i=0;i<2;i++)
    #pragma unroll
    for (int j=0;j<4;j++) acc[i][j] = (f32x4){0.f,0.f,0.f,0.f};

  const int rowA  = tid>>2,       offA = (tid&3)<<3;   // 64 rows x 4 chunks = 256
  const int rowB0 = tid>>2,       offB = (tid&3)<<3;   // 128 rows x 4 chunks = 512
  const int rowB1 = (tid+256)>>2;

  for (int k0=0;k0<K;k0+=32){
    const size_t abase = (size_t)((bsel<<4) + (k0>>6))*SS*DEPTH + (k0&63);
    GL2LDS(&Aq[abase + (size_t)(ms+rowA)*DEPTH + offA], &As[(rowA<<5)+offA]);
    GL2LDS(&Bt[(size_t)(n0+rowB0)*K + k0 + offB],       &Bs[(rowB0<<5)+offB]);
    GL2LDS(&Bt[(size_t)(n0+rowB1)*K + k0 + offB],       &Bs[(rowB1<<5)+offB]);
    __syncthreads();
    bf16x8 af[2], bfr[4];
    #pragma unroll
    for (int i=0;i<2;i++) af[i]  = *(const bf16x8*)&As[((wr + (i<<4) + ln)<<5) + (q<<3)];
    #pragma unroll
    for (int j=0;j<4;j++) bfr[j] = *(const bf16x8*)&Bs[((wc + (j<<4) + ln)<<5) + (q<<3)];
    #pragma unroll
    for (int i=0;i<2;i++)
      #pragma unroll
      for (int j=0;j<4;j++)
        acc[i][j] = __builtin_amdgcn_mfma_f32_16x16x32_bf16(af[i], bfr[j], acc[i][j], 0, 0, 0);
    __syncthreads();
  }

  #pragma unroll
  for (int i=0;i<2;i++){
    #pragma unroll
    for (int j=0;j<4;j++){
      const int n = n0 + wc + (j<<4) + ln;
      const float bv = bias[n];
      #pragma unroll
      for (int r=0;r<4;r++){
        const int mm = m0 + wr + (i<<4) + (q<<2) + r;
        out[(size_t)mm*DDIM + n] = acc[i][j][r] + bv;
      }
    }
  }
}

extern "C" void kernel_launch(void* const* d_in, const int* in_sizes, int n_in,
                              void* d_out, int out_size, void* d_ws, size_t ws_size,
                              hipStream_t stream)
{
  int ix = 0, iw = 2, ibq = 3, iwo = 4, ibo = 5;
  if (n_in == 5){ iw = 1; ibq = 2; iwo = 3; ibo = 4; }
  const float* x  = (const float*)d_in[ix];
  const float* Wq = (const float*)d_in[iw];
  const float* bq = (const float*)d_in[ibq];
  const float* Wo = (const float*)d_in[iwo];
  const float* bo = (const float*)d_in[ibo];
  float* out = (float*)d_out;

  // workspace (u16 units), total 41,943,040 B — round-1-proven footprint
  u16* ws  = (u16*)d_ws;
  u16* Wqt = ws;                                   // [3072,1024] bf16
  u16* Wot = Wqt + (size_t)QKVN*DDIM;              // [1024,1024] bf16 (bt form)
  u16* Qb  = Wot + (size_t)DDIM*DDIM;              // [B*H][S][64]; attn out aliases here
  u16* Kb  = Qb  + (size_t)BB*HH*SS*DEPTH;         // [B*H][S][64]
  u16* Vt  = Kb  + (size_t)BB*HH*SS*DEPTH;         // [B*H][64][S] (V transposed)
  u16* xb  = Vt  + (size_t)BB*HH*SS*DEPTH;         // [2,2048,1024] bf16

  convT_k<<<dim3(QKVN/32, DDIM/32), dim3(32,8), 0, stream>>>(Wq, Wqt, DDIM, QKVN);
  convT_k<<<dim3(DDIM/32, DDIM/32), dim3(32,8), 0, stream>>>(Wo, Wot, DDIM, DDIM);
  convX_k<<<dim3(BB*SS*DDIM/2048), 256, 0, stream>>>(x, xb);

  gemm_qkv_k<<<dim3(BB*SS/128, QKVN/128), 256, 0, stream>>>(xb, Wqt, bq, Qb, Kb, Vt);
  attn_k    <<<dim3(BB*HH, 32),           256, 0, stream>>>(Qb, Kb, Vt);
  gemm_out_k<<<dim3(BB*SS/64,  DDIM/128), 256, 0, stream>>>(Qb, Wot, bo, out);
}

// Round 16
// 201.336 us; speedup vs baseline: 1.3634x; 1.0549x over previous
//
#include <hip/hip_runtime.h>

#define BB 2
#define SS 2048
#define DDIM 1024
#define HH 16
#define DEPTH 64
#define QKVN (3*DDIM)

typedef unsigned short u16;
typedef unsigned int u32;
typedef __attribute__((ext_vector_type(8))) short bf16x8;
typedef __attribute__((ext_vector_type(4))) float f32x4;

__device__ __forceinline__ u16 f2bf(float f){
  union{float f; u32 u;} z; z.f=f;
  u32 r = z.u + 0x7fffu + ((z.u>>16)&1u);
  return (u16)(r>>16);
}
#define NEG_BIG (-1e30f)

// async global->LDS, 16B per lane (guide m97); LDS dest must be wave-linear (ours is tid*16B)
#define GL2LDS(gp, lp) __builtin_amdgcn_global_load_lds( \
    (const __attribute__((address_space(1))) void*)(gp), \
    (__attribute__((address_space(3))) void*)(lp), 16, 0, 0)

// ---------------- transpose+convert f32 [R,C] -> bf16 [C,R] ----------------
__global__ void convT_k(const float* __restrict__ in, u16* __restrict__ out, int R, int C){
  __shared__ float tile[32][33];
  int c0 = blockIdx.x<<5, r0 = blockIdx.y<<5;
  int tx = threadIdx.x, ty = threadIdx.y;
  for (int i=ty;i<32;i+=8) tile[i][tx] = in[(size_t)(r0+i)*C + c0+tx];
  __syncthreads();
  for (int i=ty;i<32;i+=8) out[(size_t)(c0+i)*R + r0+tx] = f2bf(tile[tx][i]);
}

// ---------------- convert f32 -> bf16 flat (both batches) ----------------
__global__ void convX_k(const float* __restrict__ in, u16* __restrict__ out){
  size_t i = ((size_t)blockIdx.x*256 + threadIdx.x) * 8;
  float4 a = *(const float4*)(in + i);
  float4 b = *(const float4*)(in + i + 4);
  ushort4 lo = { f2bf(a.x), f2bf(a.y), f2bf(a.z), f2bf(a.w) };
  ushort4 hi = { f2bf(b.x), f2bf(b.y), f2bf(b.z), f2bf(b.w) };
  *(ushort4*)(out + i)     = lo;
  *(ushort4*)(out + i + 4) = hi;
}

// ---------------- QKV GEMM (m97-style: global_load_lds staging) ----------------
// [4096,1024]@[1024,3072]^T. Epilogue splits into Qb (x0.125), Kb, Vt (V transposed).
__global__ __launch_bounds__(256,2) void gemm_qkv_k(
    const u16* __restrict__ A, const u16* __restrict__ Bt,
    const float* __restrict__ bias,
    u16* __restrict__ Qb, u16* __restrict__ Kb, u16* __restrict__ Vt)
{
  const int K = DDIM;
  __shared__ __align__(16) u16 As[128*32];
  __shared__ __align__(16) u16 Bs[128*32];
  const int tid = threadIdx.x;
  const int m0 = blockIdx.x<<7, n0 = blockIdx.y<<7;
  const int w = tid>>6, lane = tid&63, q = lane>>4, ln = lane&15;
  const int wr = (w>>1)<<6, wc = (w&1)<<6;

  f32x4 acc[4][4];
  #pragma unroll
  for (int i=0;i<4;i++)
    #pragma unroll
    for (int j=0;j<4;j++) acc[i][j] = (f32x4){0.f,0.f,0.f,0.f};

  const int row0 = tid>>2,         off0 = (tid&3)<<3;
  const int row1 = (tid+256)>>2,   off1 = (tid&3)<<3;   // (tid+256)&3 == tid&3

  for (int k0=0;k0<K;k0+=32){
    GL2LDS(&A [(size_t)(m0+row0)*K + k0 + off0], &As[(row0<<5)+off0]);
    GL2LDS(&Bt[(size_t)(n0+row0)*K + k0 + off0], &Bs[(row0<<5)+off0]);
    GL2LDS(&A [(size_t)(m0+row1)*K + k0 + off1], &As[(row1<<5)+off1]);
    GL2LDS(&Bt[(size_t)(n0+row1)*K + k0 + off1], &Bs[(row1<<5)+off1]);
    __syncthreads();
    bf16x8 af[4], bfr[4];
    #pragma unroll
    for (int i=0;i<4;i++) af[i]  = *(const bf16x8*)&As[((wr + (i<<4) + ln)<<5) + (q<<3)];
    #pragma unroll
    for (int j=0;j<4;j++) bfr[j] = *(const bf16x8*)&Bs[((wc + (j<<4) + ln)<<5) + (q<<3)];
    #pragma unroll
    for (int i=0;i<4;i++)
      #pragma unroll
      for (int j=0;j<4;j++)
        acc[i][j] = __builtin_amdgcn_mfma_f32_16x16x32_bf16(af[i], bfr[j], acc[i][j], 0, 0, 0);
    __syncthreads();
  }

  #pragma unroll
  for (int i=0;i<4;i++){
    const int mmb = m0 + wr + (i<<4) + (q<<2);         // global row (4096 range)
    const int bsel = mmb >> 11;                        // batch (uniform per block)
    const int sb   = mmb & 2047;                       // s within batch
    #pragma unroll
    for (int j=0;j<4;j++){
      const int n = n0 + wc + (j<<4) + ln;
      const int h = n / 192;
      const int rr = n - h*192;
      const int bh = (bsel<<4) + h;
      const float bv = bias[n];
      if (rr < 64){                                    // Q, scaled by 1/8
        u16* dst = Qb + (size_t)bh*SS*DEPTH + rr;
        #pragma unroll
        for (int r=0;r<4;r++) dst[(size_t)(sb+r)*DEPTH] = f2bf((acc[i][j][r] + bv)*0.125f);
      } else if (rr < 128){                            // K
        u16* dst = Kb + (size_t)bh*SS*DEPTH + (rr-64);
        #pragma unroll
        for (int r=0;r<4;r++) dst[(size_t)(sb+r)*DEPTH] = f2bf(acc[i][j][r] + bv);
      } else {                                         // V transposed: Vt[bh][d][s]
        ushort4 pv = { f2bf(acc[i][j][0] + bv), f2bf(acc[i][j][1] + bv),
                       f2bf(acc[i][j][2] + bv), f2bf(acc[i][j][3] + bv) };
        *(ushort4*)(Vt + ((size_t)bh*DEPTH + (rr-128))*SS + sb) = pv;
      }
    }
  }
}

// ---------------- MFMA flash attention (round-7 structure, QBLK=64) ----------------
// T14 async-stage + 2 barriers + MFMA ones-column row-sum (all proven at 57.5us).
// Round-16: (a) REVERT launch_bounds to (256,4) -- (256,5) squeezed VGPR 60->48 and
// spilled ~21MB/dispatch to scratch (WRITE_SIZE 8192->29696 KB), dur +17%.
// (b) T13 defer-max (THR=8): skip the alpha/rescale pass when the whole wave's
// per-row tile-max stays within m_r+8 (wave-uniform via __all; P bounded by e^8,
// scaling cancels in the final o/l divide -- guide m239 refcheck'd).
__global__ __launch_bounds__(256,4) void attn_k(
    u16* __restrict__ Qb, const u16* __restrict__ Kb, const u16* __restrict__ Vt)
{
  __shared__ __align__(16) u16 Ks[64*72];      // K tile [j][d], stride 72
  __shared__ __align__(16) u16 VsT[64*72];     // V^T tile [d][j], stride 72
  __shared__ __align__(16) u16 ps[4][16*72];   // per-wave P [m][j], stride 72

  const int tid = threadIdx.x, w = tid>>6, lane = tid&63, q = lane>>4, ln = lane&15;
  const int bh = blockIdx.x;                   // b*16 + h  (XCD = bh%8)
  const int y  = blockIdx.y, sgrp = y>>3, rr_ = y&7;
  const int qt = (sgrp==0) ? 31-rr_ : (sgrp==1) ? 16+rr_ : (sgrp==2) ? 15-rr_ : rr_;
  const int r0 = qt<<6;
  const size_t kbase = (size_t)bh*SS*DEPTH;    // Kb/Qb per-(b,h) base
  const size_t vbase = (size_t)bh*DEPTH*SS;    // Vt per-(b,h) base
  const u16* __restrict__ Kp = Kb + kbase;
  const u16* __restrict__ Vp = Vt + vbase;

  // staging geometry: chunk c = p*256+tid covers (j = c>>3, d = (c&7)*8), 512 chunks
  const int j0 = tid>>3,      d0 = (tid&7)<<3;   // p=0
  const int j1 = j0 + 32,     d1 = d0;           // p=1

  bf16x8 qf[2];
  #pragma unroll
  for (int ks=0;ks<2;ks++)
    qf[ks] = *(const bf16x8*)(Qb + kbase + (size_t)(r0 + (w<<4) + ln)*DEPTH + (ks<<5) + (q<<3));

  const bf16x8 vone = { (short)0x3F80, (short)0x3F80, (short)0x3F80, (short)0x3F80,
                        (short)0x3F80, (short)0x3F80, (short)0x3F80, (short)0x3F80 };

  f32x4 o[4];
  #pragma unroll
  for (int nt=0;nt<4;nt++) o[nt] = (f32x4){0.f,0.f,0.f,0.f};
  f32x4 lacc = (f32x4){0.f,0.f,0.f,0.f};
  float m_r[4];
  #pragma unroll
  for (int r=0;r<4;r++) m_r[r] = NEG_BIG;

  uint4 kr0, kr1, vr0, vr1;
  #define LOADT(t) do { \
    kr0 = *(const uint4*)(Kp + (size_t)(((t)<<6)+j0)*DEPTH + d0); \
    kr1 = *(const uint4*)(Kp + (size_t)(((t)<<6)+j1)*DEPTH + d1); \
    vr0 = *(const uint4*)(Vp + (size_t)j0*SS + ((t)<<6) + d0); \
    vr1 = *(const uint4*)(Vp + (size_t)j1*SS + ((t)<<6) + d1); } while(0)

  const int T = qt + 1;
  LOADT(0);                                    // prefetch tile 0
  for (int t=0;t<T;t++){
    if (t) __syncthreads();                    // all waves done reading tile t-1
    *(uint4*)&Ks [j0*72 + d0] = kr0;           // write tile t (regs already resident)
    *(uint4*)&Ks [j1*72 + d1] = kr1;
    *(uint4*)&VsT[j0*72 + d0] = vr0;
    *(uint4*)&VsT[j1*72 + d1] = vr1;
    if (t+1 < T) LOADT(t+1);                   // issue next tile's loads; land under compute
    __syncthreads();                           // tile t visible

    // QK^T
    f32x4 sc[4];
    #pragma unroll
    for (int jt=0;jt<4;jt++) sc[jt] = (f32x4){0.f,0.f,0.f,0.f};
    #pragma unroll
    for (int ks=0;ks<2;ks++){
      #pragma unroll
      for (int jt=0;jt<4;jt++){
        bf16x8 kf = *(const bf16x8*)&Ks[((jt<<4)+ln)*72 + (ks<<5) + (q<<3)];
        sc[jt] = __builtin_amdgcn_mfma_f32_16x16x32_bf16(qf[ks], kf, sc[jt], 0, 0, 0);
      }
    }

    // causal mask on diagonal tile
    if (t == T-1){
      const int rowb = r0 + (w<<4) + (q<<2);
      #pragma unroll
      for (int jt=0;jt<4;jt++){
        const int col = (t<<6) + (jt<<4) + ln;
        #pragma unroll
        for (int r=0;r<4;r++)
          if (col > rowb + r) sc[jt][r] = NEG_BIG;
      }
    }

    // row max (butterfly over the 16-lane row)
    float mt_r[4];
    #pragma unroll
    for (int r=0;r<4;r++){
      float mt = fmaxf(fmaxf(sc[0][r], sc[1][r]), fmaxf(sc[2][r], sc[3][r]));
      #pragma unroll
      for (int off=1; off<16; off<<=1) mt = fmaxf(mt, __shfl_xor(mt, off));
      mt_r[r] = mt;
    }

    // T13 defer-max: rescale only when some row's max grew past m_r + 8
    const int noresc = __all( (mt_r[0] <= m_r[0]+8.f) && (mt_r[1] <= m_r[1]+8.f)
                           && (mt_r[2] <= m_r[2]+8.f) && (mt_r[3] <= m_r[3]+8.f) );
    if (!noresc){
      #pragma unroll
      for (int r=0;r<4;r++){
        const float mnew = fmaxf(m_r[r], mt_r[r]);
        const float a = __expf(m_r[r] - mnew);
        m_r[r] = mnew;
        lacc[r] *= a;
        #pragma unroll
        for (int nt=0;nt<4;nt++) o[nt][r] *= a;
      }
    }

    // P = exp(sc - m_r) (bounded by e^8 when deferred), pack to ps
    #pragma unroll
    for (int r=0;r<4;r++){
      float p0 = __expf(sc[0][r]-m_r[r]), p1 = __expf(sc[1][r]-m_r[r]);
      float p2 = __expf(sc[2][r]-m_r[r]), p3 = __expf(sc[3][r]-m_r[r]);
      const int mrow = (q<<2) + r;
      ps[w][mrow*72 +      ln] = f2bf(p0);
      ps[w][mrow*72 + 16 + ln] = f2bf(p1);
      ps[w][mrow*72 + 32 + ln] = f2bf(p2);
      ps[w][mrow*72 + 48 + ln] = f2bf(p3);
    }

    // PV + row-sum (ps is per-wave: no barrier needed, lgkmcnt orders the RAW)
    #pragma unroll
    for (int ks=0;ks<2;ks++){
      bf16x8 pa = *(const bf16x8*)&ps[w][ln*72 + (ks<<5) + (q<<3)];
      lacc = __builtin_amdgcn_mfma_f32_16x16x32_bf16(pa, vone, lacc, 0, 0, 0);
      #pragma unroll
      for (int nt=0;nt<4;nt++){
        bf16x8 vf = *(const bf16x8*)&VsT[((nt<<4)+ln)*72 + (ks<<5) + (q<<3)];
        o[nt] = __builtin_amdgcn_mfma_f32_16x16x32_bf16(pa, vf, o[nt], 0, 0, 0);
      }
    }
  }
  #undef LOADT

  // epilogue: o/l -> bf16, overwrite this block's own Qb rows
  #pragma unroll
  for (int r=0;r<4;r++){
    const float rl = 1.f / fmaxf(lacc[r], 1e-30f);
    const int s = r0 + (w<<4) + (q<<2) + r;
    #pragma unroll
    for (int nt=0;nt<4;nt++)
      Qb[kbase + (size_t)s*DEPTH + (nt<<4) + ln] = f2bf(o[nt][r] * rl);
  }
}

// ---------------- out projection: 64x128 tile, 512 blocks = 2/CU ----------------
// A(m,k) = Qb[(m>>11)*16 + k/64][m&2047][k%64]
__global__ __launch_bounds__(256,2) void gemm_out_k(
    const u16* __restrict__ Aq, const u16* __restrict__ Bt,
    const float* __restrict__ bias, float* __restrict__ out)
{
  const int K = DDIM;
  __shared__ __align__(16) u16 As[64*32];
  __shared__ __align__(16) u16 Bs[128*32];
  const int tid = threadIdx.x;
  const int m0 = blockIdx.x<<6, n0 = blockIdx.y<<7;
  const int bsel = m0>>11, ms = m0&2047;       // batch select (uniform per block)
  const int w = tid>>6, lane = tid&63, q = lane>>4, ln = lane&15;
  const int wr = (w>>1)<<5, wc = (w&1)<<6;     // wave: 32 rows x 64 cols

  f32x4 acc[2][4];
  #pragma unroll
  for (int i=0;i<2;i++)
    #pragma unroll
    for (int j=0;j<4;j++) acc[i][j] = (f32x4){0.f,0.f,0.f,0.f};

  const int rowA  = tid>>2,       offA = (tid&3)<<3;   // 64 rows x 4 chunks = 256
  const int rowB0 = tid>>2,       offB = (tid&3)<<3;   // 128 rows x 4 chunks = 512
  const int rowB1 = (tid+256)>>2;

  for (int k0=0;k0<K;k0+=32){
    const size_t abase = (size_t)((bsel<<4) + (k0>>6))*SS*DEPTH + (k0&63);
    GL2LDS(&Aq[abase + (size_t)(ms+rowA)*DEPTH + offA], &As[(rowA<<5)+offA]);
    GL2LDS(&Bt[(size_t)(n0+rowB0)*K + k0 + offB],       &Bs[(rowB0<<5)+offB]);
    GL2LDS(&Bt[(size_t)(n0+rowB1)*K + k0 + offB],       &Bs[(rowB1<<5)+offB]);
    __syncthreads();
    bf16x8 af[2], bfr[4];
    #pragma unroll
    for (int i=0;i<2;i++) af[i]  = *(const bf16x8*)&As[((wr + (i<<4) + ln)<<5) + (q<<3)];
    #pragma unroll
    for (int j=0;j<4;j++) bfr[j] = *(const bf16x8*)&Bs[((wc + (j<<4) + ln)<<5) + (q<<3)];
    #pragma unroll
    for (int i=0;i<2;i++)
      #pragma unroll
      for (int j=0;j<4;j++)
        acc[i][j] = __builtin_amdgcn_mfma_f32_16x16x32_bf16(af[i], bfr[j], acc[i][j], 0, 0, 0);
    __syncthreads();
  }

  #pragma unroll
  for (int i=0;i<2;i++){
    #pragma unroll
    for (int j=0;j<4;j++){
      const int n = n0 + wc + (j<<4) + ln;
      const float bv = bias[n];
      #pragma unroll
      for (int r=0;r<4;r++){
        const int mm = m0 + wr + (i<<4) + (q<<2) + r;
        out[(size_t)mm*DDIM + n] = acc[i][j][r] + bv;
      }
    }
  }
}

extern "C" void kernel_launch(void* const* d_in, const int* in_sizes, int n_in,
                              void* d_out, int out_size, void* d_ws, size_t ws_size,
                              hipStream_t stream)
{
  int ix = 0, iw = 2, ibq = 3, iwo = 4, ibo = 5;
  if (n_in == 5){ iw = 1; ibq = 2; iwo = 3; ibo = 4; }
  const float* x  = (const float*)d_in[ix];
  const float* Wq = (const float*)d_in[iw];
  const float* bq = (const float*)d_in[ibq];
  const float* Wo = (const float*)d_in[iwo];
  const float* bo = (const float*)d_in[ibo];
  float* out = (float*)d_out;

  // workspace (u16 units), total 41,943,040 B — round-1-proven footprint
  u16* ws  = (u16*)d_ws;
  u16* Wqt = ws;                                   // [3072,1024] bf16
  u16* Wot = Wqt + (size_t)QKVN*DDIM;              // [1024,1024] bf16 (bt form)
  u16* Qb  = Wot + (size_t)DDIM*DDIM;              // [B*H][S][64]; attn out aliases here
  u16* Kb  = Qb  + (size_t)BB*HH*SS*DEPTH;         // [B*H][S][64]
  u16* Vt  = Kb  + (size_t)BB*HH*SS*DEPTH;         // [B*H][64][S] (V transposed)
  u16* xb  = Vt  + (size_t)BB*HH*SS*DEPTH;         // [2,2048,1024] bf16

  convT_k<<<dim3(QKVN/32, DDIM/32), dim3(32,8), 0, stream>>>(Wq, Wqt, DDIM, QKVN);
  convT_k<<<dim3(DDIM/32, DDIM/32), dim3(32,8), 0, stream>>>(Wo, Wot, DDIM, DDIM);
  convX_k<<<dim3(BB*SS*DDIM/2048), 256, 0, stream>>>(x, xb);

  gemm_qkv_k<<<dim3(BB*SS/128, QKVN/128), 256, 0, stream>>>(xb, Wqt, bq, Qb, Kb, Vt);
  attn_k    <<<dim3(BB*HH, 32),           256, 0, stream>>>(Qb, Kb, Vt);
  gemm_out_k<<<dim3(BB*SS/64,  DDIM/128), 256, 0, stream>>>(Qb, Wot, bo, out);
}

// Round 17
// 200.518 us; speedup vs baseline: 1.3689x; 1.0041x over previous
//
#include <hip/hip_runtime.h>

#define BB 2
#define SS 2048
#define DDIM 1024
#define HH 16
#define DEPTH 64
#define QKVN (3*DDIM)

typedef unsigned short u16;
typedef unsigned int u32;
typedef __attribute__((ext_vector_type(8))) short bf16x8;
typedef __attribute__((ext_vector_type(4))) float f32x4;

__device__ __forceinline__ u16 f2bf(float f){
  union{float f; u32 u;} z; z.f=f;
  u32 r = z.u + 0x7fffu + ((z.u>>16)&1u);
  return (u16)(r>>16);
}
#define NEG_BIG (-1e30f)

// async global->LDS, 16B per lane (guide m97); LDS dest must be wave-linear (ours is tid*16B)
#define GL2LDS(gp, lp) __builtin_amdgcn_global_load_lds( \
    (const __attribute__((address_space(1))) void*)(gp), \
    (__attribute__((address_space(3))) void*)(lp), 16, 0, 0)

// ---------------- transpose+convert f32 [R,C] -> bf16 [C,R] ----------------
__global__ void convT_k(const float* __restrict__ in, u16* __restrict__ out, int R, int C){
  __shared__ float tile[32][33];
  int c0 = blockIdx.x<<5, r0 = blockIdx.y<<5;
  int tx = threadIdx.x, ty = threadIdx.y;
  for (int i=ty;i<32;i+=8) tile[i][tx] = in[(size_t)(r0+i)*C + c0+tx];
  __syncthreads();
  for (int i=ty;i<32;i+=8) out[(size_t)(c0+i)*R + r0+tx] = f2bf(tile[tx][i]);
}

// ---------------- convert f32 -> bf16 flat (both batches) ----------------
__global__ void convX_k(const float* __restrict__ in, u16* __restrict__ out){
  size_t i = ((size_t)blockIdx.x*256 + threadIdx.x) * 8;
  float4 a = *(const float4*)(in + i);
  float4 b = *(const float4*)(in + i + 4);
  ushort4 lo = { f2bf(a.x), f2bf(a.y), f2bf(a.z), f2bf(a.w) };
  ushort4 hi = { f2bf(b.x), f2bf(b.y), f2bf(b.z), f2bf(b.w) };
  *(ushort4*)(out + i)     = lo;
  *(ushort4*)(out + i + 4) = hi;
}

// ---------------- QKV GEMM (m97-style: global_load_lds staging) ----------------
// [4096,1024]@[1024,3072]^T. Epilogue splits into Qb (x0.125), Kb, Vt (V transposed).
__global__ __launch_bounds__(256,2) void gemm_qkv_k(
    const u16* __restrict__ A, const u16* __restrict__ Bt,
    const float* __restrict__ bias,
    u16* __restrict__ Qb, u16* __restrict__ Kb, u16* __restrict__ Vt)
{
  const int K = DDIM;
  __shared__ __align__(16) u16 As[128*32];
  __shared__ __align__(16) u16 Bs[128*32];
  const int tid = threadIdx.x;
  const int m0 = blockIdx.x<<7, n0 = blockIdx.y<<7;
  const int w = tid>>6, lane = tid&63, q = lane>>4, ln = lane&15;
  const int wr = (w>>1)<<6, wc = (w&1)<<6;

  f32x4 acc[4][4];
  #pragma unroll
  for (int i=0;i<4;i++)
    #pragma unroll
    for (int j=0;j<4;j++) acc[i][j] = (f32x4){0.f,0.f,0.f,0.f};

  const int row0 = tid>>2,         off0 = (tid&3)<<3;
  const int row1 = (tid+256)>>2,   off1 = (tid&3)<<3;   // (tid+256)&3 == tid&3

  for (int k0=0;k0<K;k0+=32){
    GL2LDS(&A [(size_t)(m0+row0)*K + k0 + off0], &As[(row0<<5)+off0]);
    GL2LDS(&Bt[(size_t)(n0+row0)*K + k0 + off0], &Bs[(row0<<5)+off0]);
    GL2LDS(&A [(size_t)(m0+row1)*K + k0 + off1], &As[(row1<<5)+off1]);
    GL2LDS(&Bt[(size_t)(n0+row1)*K + k0 + off1], &Bs[(row1<<5)+off1]);
    __syncthreads();
    bf16x8 af[4], bfr[4];
    #pragma unroll
    for (int i=0;i<4;i++) af[i]  = *(const bf16x8*)&As[((wr + (i<<4) + ln)<<5) + (q<<3)];
    #pragma unroll
    for (int j=0;j<4;j++) bfr[j] = *(const bf16x8*)&Bs[((wc + (j<<4) + ln)<<5) + (q<<3)];
    #pragma unroll
    for (int i=0;i<4;i++)
      #pragma unroll
      for (int j=0;j<4;j++)
        acc[i][j] = __builtin_amdgcn_mfma_f32_16x16x32_bf16(af[i], bfr[j], acc[i][j], 0, 0, 0);
    __syncthreads();
  }

  #pragma unroll
  for (int i=0;i<4;i++){
    const int mmb = m0 + wr + (i<<4) + (q<<2);         // global row (4096 range)
    const int bsel = mmb >> 11;                        // batch (uniform per block)
    const int sb   = mmb & 2047;                       // s within batch
    #pragma unroll
    for (int j=0;j<4;j++){
      const int n = n0 + wc + (j<<4) + ln;
      const int h = n / 192;
      const int rr = n - h*192;
      const int bh = (bsel<<4) + h;
      const float bv = bias[n];
      if (rr < 64){                                    // Q, scaled by 1/8
        u16* dst = Qb + (size_t)bh*SS*DEPTH + rr;
        #pragma unroll
        for (int r=0;r<4;r++) dst[(size_t)(sb+r)*DEPTH] = f2bf((acc[i][j][r] + bv)*0.125f);
      } else if (rr < 128){                            // K
        u16* dst = Kb + (size_t)bh*SS*DEPTH + (rr-64);
        #pragma unroll
        for (int r=0;r<4;r++) dst[(size_t)(sb+r)*DEPTH] = f2bf(acc[i][j][r] + bv);
      } else {                                         // V transposed: Vt[bh][d][s]
        ushort4 pv = { f2bf(acc[i][j][0] + bv), f2bf(acc[i][j][1] + bv),
                       f2bf(acc[i][j][2] + bv), f2bf(acc[i][j][3] + bv) };
        *(ushort4*)(Vt + ((size_t)bh*DEPTH + (rr-128))*SS + sb) = pv;
      }
    }
  }
}

// ---------------- MFMA flash attention: KVBLK=128, QBLK=64, grid (32,32) ----------------
// Round-17: double the K/V tile to 128 columns. Per column, MFMA/exp/ps work is
// unchanged; per column the FIXED costs halve (2 barriers, LOADT bookkeeping, T13
// ballot/branch, butterfly stages, pa/lacc overhead). Block-iters 16896 -> 8704.
// Grid stays (32,32) -- round-8's failure was grid halving + imbalance, not tiling.
// LDS 53,248B -> 3 blocks/CU cap; measured occupancy was ~2.4 blocks effective
// (tail-limited, not resource-capped), so the 4->3 cap rarely binds.
// Keeps: T14 async-stage (reg prefetch), MFMA ones-column row-sum, T13 defer-max.
// Causality: generic mask on t==T-1 covers diagonal AND (qt even) the fully-future
// upper 64 columns; staging never OOB (max col = 2047).
__global__ __launch_bounds__(256,3) void attn_k(
    u16* __restrict__ Qb, const u16* __restrict__ Kb, const u16* __restrict__ Vt)
{
  __shared__ __align__(16) u16 Ks[128*72];     // K tile [j=0..127][d], stride 72
  __shared__ __align__(16) u16 VsT[64*136];    // V^T tile [d][j=0..127], stride 136
  __shared__ __align__(16) u16 ps[4][16*136];  // per-wave P [m][j], stride 136

  const int tid = threadIdx.x, w = tid>>6, lane = tid&63, q = lane>>4, ln = lane&15;
  const int bh = blockIdx.x;                   // b*16 + h  (XCD = bh%8)
  const int y  = blockIdx.y, sgrp = y>>3, rr_ = y&7;
  const int qt = (sgrp==0) ? 31-rr_ : (sgrp==1) ? 16+rr_ : (sgrp==2) ? 15-rr_ : rr_;
  const int r0 = qt<<6;
  const size_t kbase = (size_t)bh*SS*DEPTH;    // Kb/Qb per-(b,h) base
  const size_t vbase = (size_t)bh*DEPTH*SS;    // Vt per-(b,h) base
  const u16* __restrict__ Kp = Kb + kbase;
  const u16* __restrict__ Vp = Vt + vbase;

  // staging geometry (1024 chunks of 16B each for K and V, 4 per thread):
  // K: row = p*32 + (tid>>3), dcol = (tid&7)*8 ; V: drow = p*16 + (tid>>4), scol = (tid&15)*8
  const int kjr = tid>>3, kdc = (tid&7)<<3;
  const int vdr = tid>>4, vsc = (tid&15)<<3;

  bf16x8 qf[2];
  #pragma unroll
  for (int ksd=0;ksd<2;ksd++)
    qf[ksd] = *(const bf16x8*)(Qb + kbase + (size_t)(r0 + (w<<4) + ln)*DEPTH + (ksd<<5) + (q<<3));

  const bf16x8 vone = { (short)0x3F80, (short)0x3F80, (short)0x3F80, (short)0x3F80,
                        (short)0x3F80, (short)0x3F80, (short)0x3F80, (short)0x3F80 };

  f32x4 o[4];
  #pragma unroll
  for (int nt=0;nt<4;nt++) o[nt] = (f32x4){0.f,0.f,0.f,0.f};
  f32x4 lacc = (f32x4){0.f,0.f,0.f,0.f};
  float m_r[4];
  #pragma unroll
  for (int r=0;r<4;r++) m_r[r] = NEG_BIG;

  uint4 kr0, kr1, kr2, kr3, vr0, vr1, vr2, vr3;
  #define LOADT(t) do { \
    kr0 = *(const uint4*)(Kp + (size_t)(((t)<<7) +      kjr)*DEPTH + kdc); \
    kr1 = *(const uint4*)(Kp + (size_t)(((t)<<7) + 32 + kjr)*DEPTH + kdc); \
    kr2 = *(const uint4*)(Kp + (size_t)(((t)<<7) + 64 + kjr)*DEPTH + kdc); \
    kr3 = *(const uint4*)(Kp + (size_t)(((t)<<7) + 96 + kjr)*DEPTH + kdc); \
    vr0 = *(const uint4*)(Vp + (size_t)(     vdr)*SS + ((t)<<7) + vsc); \
    vr1 = *(const uint4*)(Vp + (size_t)(16 + vdr)*SS + ((t)<<7) + vsc); \
    vr2 = *(const uint4*)(Vp + (size_t)(32 + vdr)*SS + ((t)<<7) + vsc); \
    vr3 = *(const uint4*)(Vp + (size_t)(48 + vdr)*SS + ((t)<<7) + vsc); } while(0)

  const int T = (qt>>1) + 1;                   // 128-wide tiles
  LOADT(0);                                    // prefetch tile 0
  for (int t=0;t<T;t++){
    if (t) __syncthreads();                    // all waves done reading tile t-1
    *(uint4*)&Ks [(     kjr)*72  + kdc] = kr0; // write tile t (regs already resident)
    *(uint4*)&Ks [(32 + kjr)*72  + kdc] = kr1;
    *(uint4*)&Ks [(64 + kjr)*72  + kdc] = kr2;
    *(uint4*)&Ks [(96 + kjr)*72  + kdc] = kr3;
    *(uint4*)&VsT[(     vdr)*136 + vsc] = vr0;
    *(uint4*)&VsT[(16 + vdr)*136 + vsc] = vr1;
    *(uint4*)&VsT[(32 + vdr)*136 + vsc] = vr2;
    *(uint4*)&VsT[(48 + vdr)*136 + vsc] = vr3;
    if (t+1 < T) LOADT(t+1);                   // issue next tile's loads; land under compute
    __syncthreads();                           // tile t visible

    // QK^T (8 column-subtiles x 2 d-halves)
    f32x4 sc[8];
    #pragma unroll
    for (int jt=0;jt<8;jt++) sc[jt] = (f32x4){0.f,0.f,0.f,0.f};
    #pragma unroll
    for (int ksd=0;ksd<2;ksd++){
      #pragma unroll
      for (int jt=0;jt<8;jt++){
        bf16x8 kf = *(const bf16x8*)&Ks[((jt<<4)+ln)*72 + (ksd<<5) + (q<<3)];
        sc[jt] = __builtin_amdgcn_mfma_f32_16x16x32_bf16(qf[ksd], kf, sc[jt], 0, 0, 0);
      }
    }

    // causal mask on the last tile (covers diagonal + fully-future upper half)
    if (t == T-1){
      const int rowb = r0 + (w<<4) + (q<<2);
      #pragma unroll
      for (int jt=0;jt<8;jt++){
        const int col = (t<<7) + (jt<<4) + ln;
        #pragma unroll
        for (int r=0;r<4;r++)
          if (col > rowb + r) sc[jt][r] = NEG_BIG;
      }
    }

    // row max (8-frag chain + 16-lane butterfly)
    float mt_r[4];
    #pragma unroll
    for (int r=0;r<4;r++){
      float m01 = fmaxf(sc[0][r], sc[1][r]), m23 = fmaxf(sc[2][r], sc[3][r]);
      float m45 = fmaxf(sc[4][r], sc[5][r]), m67 = fmaxf(sc[6][r], sc[7][r]);
      float mt = fmaxf(fmaxf(m01, m23), fmaxf(m45, m67));
      #pragma unroll
      for (int off=1; off<16; off<<=1) mt = fmaxf(mt, __shfl_xor(mt, off));
      mt_r[r] = mt;
    }

    // T13 defer-max: rescale only when some row's max grew past m_r + 8
    const int noresc = __all( (mt_r[0] <= m_r[0]+8.f) && (mt_r[1] <= m_r[1]+8.f)
                           && (mt_r[2] <= m_r[2]+8.f) && (mt_r[3] <= m_r[3]+8.f) );
    if (!noresc){
      #pragma unroll
      for (int r=0;r<4;r++){
        const float mnew = fmaxf(m_r[r], mt_r[r]);
        const float a = __expf(m_r[r] - mnew);
        m_r[r] = mnew;
        lacc[r] *= a;
        #pragma unroll
        for (int nt=0;nt<4;nt++) o[nt][r] *= a;
      }
    }

    // P = exp(sc - m_r) (bounded by e^8 when deferred), pack to ps
    #pragma unroll
    for (int r=0;r<4;r++){
      const int mrow = (q<<2) + r;
      #pragma unroll
      for (int jt=0;jt<8;jt++)
        ps[w][mrow*136 + (jt<<4) + ln] = f2bf(__expf(sc[jt][r] - m_r[r]));
    }

    // PV + row-sum over 4 k-slices (ps is per-wave: lgkmcnt orders the RAW)
    #pragma unroll
    for (int ks=0;ks<4;ks++){
      bf16x8 pa = *(const bf16x8*)&ps[w][ln*136 + (ks<<5) + (q<<3)];
      lacc = __builtin_amdgcn_mfma_f32_16x16x32_bf16(pa, vone, lacc, 0, 0, 0);
      #pragma unroll
      for (int nt=0;nt<4;nt++){
        bf16x8 vf = *(const bf16x8*)&VsT[((nt<<4)+ln)*136 + (ks<<5) + (q<<3)];
        o[nt] = __builtin_amdgcn_mfma_f32_16x16x32_bf16(pa, vf, o[nt], 0, 0, 0);
      }
    }
  }
  #undef LOADT

  // epilogue: o/l -> bf16, overwrite this block's own Qb rows
  #pragma unroll
  for (int r=0;r<4;r++){
    const float rl = 1.f / fmaxf(lacc[r], 1e-30f);
    const int s = r0 + (w<<4) + (q<<2) + r;
    #pragma unroll
    for (int nt=0;nt<4;nt++)
      Qb[kbase + (size_t)s*DEPTH + (nt<<4) + ln] = f2bf(o[nt][r] * rl);
  }
}

// ---------------- out projection: 64x128 tile, 512 blocks = 2/CU ----------------
// A(m,k) = Qb[(m>>11)*16 + k/64][m&2047][k%64]
__global__ __launch_bounds__(256,2) void gemm_out_k(
    const u16* __restrict__ Aq, const u16* __restrict__ Bt,
    const float* __restrict__ bias, float* __restrict__ out)
{
  const int K = DDIM;
  __shared__ __align__(16) u16 As[64*32];
  __shared__ __align__(16) u16 Bs[128*32];
  const int tid = threadIdx.x;
  const int m0 = blockIdx.x<<6, n0 = blockIdx.y<<7;
  const int bsel = m0>>11, ms = m0&2047;       // batch select (uniform per block)
  const int w = tid>>6, lane = tid&63, q = lane>>4, ln = lane&15;
  const int wr = (w>>1)<<5, wc = (w&1)<<6;     // wave: 32 rows x 64 cols

  f32x4 acc[2][4];
  #pragma unroll
  for (int i=0;i<2;i++)
    #pragma unroll
    for (int j=0;j<4;j++) acc[i][j] = (f32x4){0.f,0.f,0.f,0.f};

  const int rowA  = tid>>2,       offA = (tid&3)<<3;   // 64 rows x 4 chunks = 256
  const int rowB0 = tid>>2,       offB = (tid&3)<<3;   // 128 rows x 4 chunks = 512
  const int rowB1 = (tid+256)>>2;

  for (int k0=0;k0<K;k0+=32){
    const size_t abase = (size_t)((bsel<<4) + (k0>>6))*SS*DEPTH + (k0&63);
    GL2LDS(&Aq[abase + (size_t)(ms+rowA)*DEPTH + offA], &As[(rowA<<5)+offA]);
    GL2LDS(&Bt[(size_t)(n0+rowB0)*K + k0 + offB],       &Bs[(rowB0<<5)+offB]);
    GL2LDS(&Bt[(size_t)(n0+rowB1)*K + k0 + offB],       &Bs[(rowB1<<5)+offB]);
    __syncthreads();
    bf16x8 af[2], bfr[4];
    #pragma unroll
    for (int i=0;i<2;i++) af[i]  = *(const bf16x8*)&As[((wr + (i<<4) + ln)<<5) + (q<<3)];
    #pragma unroll
    for (int j=0;j<4;j++) bfr[j] = *(const bf16x8*)&Bs[((wc + (j<<4) + ln)<<5) + (q<<3)];
    #pragma unroll
    for (int i=0;i<2;i++)
      #pragma unroll
      for (int j=0;j<4;j++)
        acc[i][j] = __builtin_amdgcn_mfma_f32_16x16x32_bf16(af[i], bfr[j], acc[i][j], 0, 0, 0);
    __syncthreads();
  }

  #pragma unroll
  for (int i=0;i<2;i++){
    #pragma unroll
    for (int j=0;j<4;j++){
      const int n = n0 + wc + (j<<4) + ln;
      const float bv = bias[n];
      #pragma unroll
      for (int r=0;r<4;r++){
        const int mm = m0 + wr + (i<<4) + (q<<2) + r;
        out[(size_t)mm*DDIM + n] = acc[i][j][r] + bv;
      }
    }
  }
}

extern "C" void kernel_launch(void* const* d_in, const int* in_sizes, int n_in,
                              void* d_out, int out_size, void* d_ws, size_t ws_size,
                              hipStream_t stream)
{
  int ix = 0, iw = 2, ibq = 3, iwo = 4, ibo = 5;
  if (n_in == 5){ iw = 1; ibq = 2; iwo = 3; ibo = 4; }
  const float* x  = (const float*)d_in[ix];
  const float* Wq = (const float*)d_in[iw];
  const float* bq = (const float*)d_in[ibq];
  const float* Wo = (const float*)d_in[iwo];
  const float* bo = (const float*)d_in[ibo];
  float* out = (float*)d_out;

  // workspace (u16 units), total 41,943,040 B — round-1-proven footprint
  u16* ws  = (u16*)d_ws;
  u16* Wqt = ws;                                   // [3072,1024] bf16
  u16* Wot = Wqt + (size_t)QKVN*DDIM;              // [1024,1024] bf16 (bt form)
  u16* Qb  = Wot + (size_t)DDIM*DDIM;              // [B*H][S][64]; attn out aliases here
  u16* Kb  = Qb  + (size_t)BB*HH*SS*DEPTH;         // [B*H][S][64]
  u16* Vt  = Kb  + (size_t)BB*HH*SS*DEPTH;         // [B*H][64][S] (V transposed)
  u16* xb  = Vt  + (size_t)BB*HH*SS*DEPTH;         // [2,2048,1024] bf16

  convT_k<<<dim3(QKVN/32, DDIM/32), dim3(32,8), 0, stream>>>(Wq, Wqt, DDIM, QKVN);
  convT_k<<<dim3(DDIM/32, DDIM/32), dim3(32,8), 0, stream>>>(Wo, Wot, DDIM, DDIM);
  convX_k<<<dim3(BB*SS*DDIM/2048), 256, 0, stream>>>(x, xb);

  gemm_qkv_k<<<dim3(BB*SS/128, QKVN/128), 256, 0, stream>>>(xb, Wqt, bq, Qb, Kb, Vt);
  attn_k    <<<dim3(BB*HH, 32),           256, 0, stream>>>(Qb, Kb, Vt);
  gemm_out_k<<<dim3(BB*SS/64,  DDIM/128), 256, 0, stream>>>(Qb, Wot, bo, out);
}